// Round 16
// baseline (302.058 us; speedup 1.0000x reference)
//
#include <hip/hip_runtime.h>
#include <math.h>

// B=8, N=1024, D=256, C=8192
#define QROWS 8192
#define DDIM  256
#define CCNT  8192

typedef __attribute__((ext_vector_type(4))) float f32x4;
typedef __attribute__((ext_vector_type(8))) short bf16x8;

__device__ __forceinline__ unsigned short f2bf(float f) {
    unsigned u = __float_as_uint(f);
    u += 0x7fffu + ((u >> 16) & 1u);          // round-to-nearest-even
    return (unsigned short)(u >> 16);
}
__device__ __forceinline__ unsigned u32max(unsigned a, unsigned b) { return a > b ? a : b; }
__device__ __forceinline__ unsigned u32min(unsigned a, unsigned b) { return a < b ? a : b; }

// 2-op monotone key (positives exact-ordered; negatives scrambled but always lose;
// fixup re-scores candidates in exact f32, so only the candidate SET matters)
__device__ __forceinline__ unsigned key32(float v, unsigned enc) {
    return ((__float_as_uint(v) ^ 0x80000000u) & 0xFFFFFF00u) | enc;
}

// ---------- merged prep: x -> bf16 ; e -> l2-normalized bf16 ----------
__global__ void k_prep(const float* __restrict__ x, unsigned short* __restrict__ xb,
                       const float* __restrict__ e, unsigned short* __restrict__ eb) {
    const int bid = blockIdx.x;
    if (bid < 1024) {                         // x: 1024 blocks, 8 el/thread
        const int i = (bid * 256 + threadIdx.x) * 8;
        const float4 f0 = *reinterpret_cast<const float4*>(x + i);
        const float4 f1 = *reinterpret_cast<const float4*>(x + i + 4);
        uint4 o;
        o.x = f2bf(f0.x) | ((unsigned)f2bf(f0.y) << 16);
        o.y = f2bf(f0.z) | ((unsigned)f2bf(f0.w) << 16);
        o.z = f2bf(f1.x) | ((unsigned)f2bf(f1.y) << 16);
        o.w = f2bf(f1.z) | ((unsigned)f2bf(f1.w) << 16);
        *reinterpret_cast<uint4*>(xb + i) = o;
    } else {                                  // e: 2048 blocks, 4 rows/block
        const int row  = (bid - 1024) * 4 + (threadIdx.x >> 6);
        const int lane = threadIdx.x & 63;
        const float4 v = *reinterpret_cast<const float4*>(e + (size_t)row * DDIM + lane * 4);
        float s = v.x * v.x + v.y * v.y + v.z * v.z + v.w * v.w;
        #pragma unroll
        for (int off = 1; off < 64; off <<= 1) s += __shfl_xor(s, off);
        const float inv = 1.0f / fmaxf(sqrtf(s), 1e-12f);
        ushort4 o;
        o.x = f2bf(v.x * inv); o.y = f2bf(v.y * inv);
        o.z = f2bf(v.z * inv); o.w = f2bf(v.w * inv);
        *reinterpret_cast<ushort4*>(eb + (size_t)row * DDIM + lane * 4) = o;
    }
}

#define GLOAD_LDS(g, s) \
    __builtin_amdgcn_global_load_lds((const __attribute__((address_space(1))) void*)(g), \
                                     (__attribute__((address_space(3))) void*)(s), 16, 0, 0)

#define SBAR do { asm volatile("" ::: "memory"); __builtin_amdgcn_s_barrier(); \
                  asm volatile("" ::: "memory"); } while (0)
#define WAIT_LGKM(n) do { asm volatile("s_waitcnt lgkmcnt(" #n ")" ::: "memory"); \
                          __builtin_amdgcn_sched_barrier(0); } while (0)
#define WAIT_VM(n) do { asm volatile("s_waitcnt vmcnt(" #n ")" ::: "memory"); \
                        __builtin_amdgcn_sched_barrier(0); } while (0)

// ---------- GEMM: 4 waves/block, 3 blocks/CU (48 KB LDS); A in regs via LDS ----------
// grid 512 = 32 panels (256 rows) x 16 splits (512 cols); block = 4 waves x 64 rows.
// LDS 48 KB = 6-slot B ring x 8 KB (16 cols x 512 B); A prologue uses first 32 KB
// in 4 serial rounds (rows r*64..r*64+63, read by wave r -> 128 VGPR aF).
// Rows 512 B = 32 chunks of 16 B; phys chunk = (p&24)|((p&7)^(row&7)), src pre-swizzled.
// Pair pacing: u=0..15, steady WAIT_VM(4) -> SBAR -> STAGEB pair u+2 -> 2 TILEs.
// 3 independent blocks/CU cover each other's sync stalls (m114 mechanism).
__launch_bounds__(256, 3)
__global__ void k_gemm(const unsigned short* __restrict__ xb,
                       const unsigned short* __restrict__ eb,
                       unsigned* pout /* aliases d_out */) {
    extern __shared__ char smem[];

    const int tid = threadIdx.x;
    const int w = tid >> 6, l = tid & 63;
    const int lg = l >> 4, lr = l & 15, lr7 = lr & 7;
    const int bid = blockIdx.x;
    const int q = bid >> 3;
    const int panel = (bid & 7) * 4 + (q >> 4);       // XCD x owns panels 4x..4x+3
    const int split = q & 15;
    const int n0 = panel * 256, c0 = split * 512;

    // ---- staging lane constants: thread t covers chunk c = g*256 + t ----
    const int lchk = (tid & 24) | ((tid & 7) ^ ((tid >> 5) & 7));
    const char* baseA = (const char*)xb + (size_t)(n0 + (tid >> 5)) * 512 + lchk * 16;
    const char* baseB = (const char*)eb + (size_t)(c0 + (tid >> 5)) * 512 + lchk * 16;
    const int wl16 = w * 1024;                 // wave-uniform LDS base

#define STAGE_AQ(r) do { _Pragma("unroll") for (int g_ = 0; g_ < 8; ++g_)                  \
    GLOAD_LDS(baseA + (r) * 32768 + g_ * 4096, smem + g_ * 4096 + wl16); } while (0)
#define STAGEB(t) do { _Pragma("unroll") for (int g_ = 0; g_ < 2; ++g_)                    \
    GLOAD_LDS(baseB + (size_t)(t) * 8192 + g_ * 4096,                                      \
              smem + ((t) % 6) * 8192 + g_ * 4096 + wl16); } while (0)

    // ---- A fragments: 64 rows x 256 K per wave = 128 VGPR (read during round w) ----
    bf16x8 aF[4][8];
#define READA() do { _Pragma("unroll") for (int mi_ = 0; mi_ < 4; ++mi_)                   \
    _Pragma("unroll") for (int kk_ = 0; kk_ < 8; ++kk_) {                                  \
        const int lc_ = kk_ * 4 + lg;                                                      \
        const int ph_ = (lc_ & 24) | ((lc_ & 7) ^ lr7);                                    \
        aF[mi_][kk_] = *reinterpret_cast<const bf16x8*>(                                   \
            smem + (mi_ * 16 + lr) * 512 + ph_ * 16); } } while (0)

    // ---- prologue: 4 serial A rounds (32 KB each), wave r reads round r ----
    #pragma unroll
    for (int r = 0; r < 4; ++r) {
        STAGE_AQ(r);
        WAIT_VM(0); SBAR;
        if (w == r) READA();
        WAIT_LGKM(0); SBAR;                    // readers drained before next overwrite
    }
    STAGEB(0); STAGEB(1); STAGEB(2); STAGEB(3);   // pairs 0,1 (8 loads in flight)

    // ---- main loop state ----
    const f32x4 zf4 = {0.f, 0.f, 0.f, 0.f};
    unsigned rk1[16], rk2[16];
    #pragma unroll
    for (int i = 0; i < 16; ++i) { rk1[i] = 0u; rk2[i] = 0u; }

// One 16-col tile: 8 kk x {1 ds_read_b128, 4 MFMA}; kk=0 zero-C; 2-op-key TILEEND.
#define TILE(t) do {                                                                       \
    const char* sb_ = smem + ((t) % 6) * 8192;                                             \
    f32x4 ac_[4];                                                                          \
    {                                                                                      \
        const int ph0_ = ((lg & 24) | ((lg & 7) ^ lr7)) * 16;                              \
        const bf16x8 b_ = *reinterpret_cast<const bf16x8*>(sb_ + lr * 512 + ph0_);         \
        _Pragma("unroll") for (int mi_ = 0; mi_ < 4; ++mi_)                                \
            ac_[mi_] = __builtin_amdgcn_mfma_f32_16x16x32_bf16(aF[mi_][0], b_, zf4, 0, 0, 0); \
    }                                                                                      \
    _Pragma("unroll") for (int kk_ = 1; kk_ < 8; ++kk_) {                                  \
        const int lc_ = kk_ * 4 + lg;                                                      \
        const int ph_ = ((lc_ & 24) | ((lc_ & 7) ^ lr7)) * 16;                             \
        const bf16x8 b_ = *reinterpret_cast<const bf16x8*>(sb_ + lr * 512 + ph_);          \
        _Pragma("unroll") for (int mi_ = 0; mi_ < 4; ++mi_)                                \
            ac_[mi_] = __builtin_amdgcn_mfma_f32_16x16x32_bf16(aF[mi_][kk_], b_, ac_[mi_], 0, 0, 0); \
    }                                                                                      \
    const unsigned encb_ = (unsigned)(255 - ((t) & 15) * 16) - (unsigned)lr;               \
    _Pragma("unroll") for (int mi_ = 0; mi_ < 4; ++mi_)                                    \
        _Pragma("unroll") for (int rr_ = 0; rr_ < 4; ++rr_) {                              \
            const unsigned q_ = key32(ac_[mi_][rr_], encb_);                               \
            const int i_ = mi_ * 4 + rr_;                                                  \
            const unsigned lo_ = u32min(rk1[i_], q_);                                      \
            rk1[i_] = u32max(rk1[i_], q_);                                                 \
            rk2[i_] = u32max(rk2[i_], lo_);                                                \
        }                                                                                  \
} while (0)

// flush: merge the 16 lr-lanes' running top-2, store this half's partials, reset
#define FLUSH(half) do {                                                                   \
    _Pragma("unroll") for (int i_ = 0; i_ < 16; ++i_) {                                    \
        unsigned t1_ = rk1[i_], t2_ = rk2[i_];                                             \
        _Pragma("unroll") for (int off_ = 1; off_ < 16; off_ <<= 1) {                      \
            const unsigned o1_ = __shfl_xor(t1_, off_);                                    \
            const unsigned o2_ = __shfl_xor(t2_, off_);                                    \
            const unsigned n1_ = u32max(t1_, o1_), lo_ = u32min(t1_, o1_);                 \
            t2_ = u32max(u32max(t2_, o2_), lo_);                                           \
            t1_ = n1_;                                                                     \
        }                                                                                  \
        if (lr == 0) {                                                                     \
            const int row_ = n0 + w * 64 + (i_ >> 2) * 16 + lg * 4 + (i_ & 3);             \
            uint2 o_; o_.x = t1_; o_.y = t2_;                                              \
            *reinterpret_cast<uint2*>(pout + (size_t)row_ * 256 + split * 4 + (half) * 2) = o_; \
        }                                                                                  \
        rk1[i_] = 0u; rk2[i_] = 0u;                                                        \
    }                                                                                      \
} while (0)

    // ---- 16 pairs of 16-col tiles; one WAIT_VM + SBAR per pair ----
    // FIFO (per wave, 2 loads/tile): entering u, outstanding = pairs u, u+1 (8 loads);
    // VM(4) retires pair u; SBAR certifies on all waves; STAGEB(pair u+2) overwrites
    // slots (2u+4)%6 = (2u-2)%6 whose last readers (pair u-1) all passed SBAR(u) -> WAR
    // safe. FLUSH(0) stores at u=7 cause one bounded over-wait at u=8 (r13-proven).
    WAIT_VM(4); SBAR;
    #pragma unroll 1
    for (int u = 0; u < 16; ++u) {
        if (u >= 1) {
            if (u < 15) { WAIT_VM(4); } else { WAIT_VM(0); }
            SBAR;
        }
        if (u <= 13) { STAGEB(2 * u + 4); STAGEB(2 * u + 5); }
        TILE(2 * u);
        TILE(2 * u + 1);
        if (u == 7)  FLUSH(0);                // tiles 0-15 = first 256-col half
        if (u == 15) FLUSH(1);                // second half
    }
#undef STAGE_AQ
#undef STAGEB
#undef READA
#undef TILE
#undef FLUSH
}

// ---------- fixup: global top-4 of 64 keys -> exact f32 -> argmax + gather ----------
__global__ void k_fixup(const unsigned* pk,  // == (u32*)d_out, intentionally no restrict
                        const float* __restrict__ x, const float* __restrict__ e,
                        float* out) {
    const int row = blockIdx.x * 4 + (threadIdx.x >> 6);
    const int t   = threadIdx.x & 63;   // t<32: half-split partial holder (256 cols each)
    unsigned long long kk0 = 0ull, kk1 = 0ull;
    if (t < 32) {
        const uint2 kv = reinterpret_cast<const uint2*>(pk + (size_t)row * 256)[t];
        const int col0 = t * 256 + 255 - (int)(kv.x & 255u);
        kk0 = ((unsigned long long)(kv.x & 0xFFFFFF00u) << 32) | (unsigned)(~col0);
        const int col1 = t * 256 + 255 - (int)(kv.y & 255u);
        kk1 = ((unsigned long long)(kv.y & 0xFFFFFF00u) << 32) | (unsigned)(~col1);
    }

    int cand[4];
    #pragma unroll
    for (int p = 0; p < 4; ++p) {
        unsigned long long m = kk0 > kk1 ? kk0 : kk1;
        #pragma unroll
        for (int off = 1; off < 64; off <<= 1) {
            const unsigned long long o = __shfl_xor(m, off);
            if (o > m) m = o;
        }
        cand[p] = (int)(~(unsigned)m) & (CCNT - 1);
        if (kk0 == m) kk0 = 0ull;
        if (kk1 == m) kk1 = 0ull;
    }

    const float4 xv = *reinterpret_cast<const float4*>(x + (size_t)row * DDIM + t * 4);
    float best = -INFINITY; int bc = 0x7fffffff;
    #pragma unroll
    for (int p = 0; p < 4; ++p) {
        const int c = cand[p];
        const float4 ev = *reinterpret_cast<const float4*>(e + (size_t)c * DDIM + t * 4);
        float d  = xv.x * ev.x + xv.y * ev.y + xv.z * ev.z + xv.w * ev.w;
        float ss = ev.x * ev.x + ev.y * ev.y + ev.z * ev.z + ev.w * ev.w;
        #pragma unroll
        for (int off = 1; off < 64; off <<= 1) {
            d  += __shfl_xor(d, off);
            ss += __shfl_xor(ss, off);
        }
        const float v = d * (1.0f / fmaxf(sqrtf(ss), 1e-12f));
        if (v > best || (v == best && c < bc)) { best = v; bc = c; }
    }

    if (t == 0) out[(size_t)QROWS * DDIM + row] = (float)bc;
    const float4 qv = *reinterpret_cast<const float4*>(e + (size_t)bc * DDIM + t * 4);
    *reinterpret_cast<float4*>(out + (size_t)row * DDIM + t * 4) = qv; // overwrites this row's partials only
}

extern "C" void kernel_launch(void* const* d_in, const int* in_sizes, int n_in,
                              void* d_out, int out_size, void* d_ws, size_t ws_size,
                              hipStream_t stream) {
    const float* x = (const float*)d_in[0];
    const float* e = (const float*)d_in[1];
    float* out = (float*)d_out;
    char* ws = (char*)d_ws;

    unsigned short* xb = (unsigned short*)ws;                             // 4 MB
    unsigned short* eb = (unsigned short*)(ws + (size_t)4 * 1024 * 1024); // 4 MB

    hipFuncSetAttribute(reinterpret_cast<const void*>(k_gemm),
                        hipFuncAttributeMaxDynamicSharedMemorySize, 49152);

    k_prep<<<3072, 256, 0, stream>>>(x, xb, e, eb);
    k_gemm<<<512, 256, 49152, stream>>>(xb, eb, (unsigned*)d_out);
    k_fixup<<<QROWS / 4, 256, 0, stream>>>((const unsigned*)d_out, x, e, out);
}

// Round 17
// 66.183 us; speedup vs baseline: 4.5640x; 4.5640x over previous
//
#include <hip/hip_runtime.h>
#include <math.h>

// B=8, N=1024, D=256, C=8192
#define QROWS 8192
#define DDIM  256
#define CCNT  8192

typedef __attribute__((ext_vector_type(4))) float f32x4;
typedef __attribute__((ext_vector_type(8))) short bf16x8;

__device__ __forceinline__ unsigned short f2bf(float f) {
    unsigned u = __float_as_uint(f);
    u += 0x7fffu + ((u >> 16) & 1u);          // round-to-nearest-even
    return (unsigned short)(u >> 16);
}
__device__ __forceinline__ unsigned u32max(unsigned a, unsigned b) { return a > b ? a : b; }
__device__ __forceinline__ unsigned u32min(unsigned a, unsigned b) { return a < b ? a : b; }

// 2-op monotone key (positives exact-ordered; negatives scrambled but always lose;
// fixup re-scores candidates in exact f32, so only the candidate SET matters)
__device__ __forceinline__ unsigned key32(float v, unsigned enc) {
    return ((__float_as_uint(v) ^ 0x80000000u) & 0xFFFFFF00u) | enc;
}

// ---------- merged prep: x -> bf16 ; e -> l2-normalized bf16 ----------
__global__ void k_prep(const float* __restrict__ x, unsigned short* __restrict__ xb,
                       const float* __restrict__ e, unsigned short* __restrict__ eb) {
    const int bid = blockIdx.x;
    if (bid < 1024) {                         // x: 1024 blocks, 8 el/thread
        const int i = (bid * 256 + threadIdx.x) * 8;
        const float4 f0 = *reinterpret_cast<const float4*>(x + i);
        const float4 f1 = *reinterpret_cast<const float4*>(x + i + 4);
        uint4 o;
        o.x = f2bf(f0.x) | ((unsigned)f2bf(f0.y) << 16);
        o.y = f2bf(f0.z) | ((unsigned)f2bf(f0.w) << 16);
        o.z = f2bf(f1.x) | ((unsigned)f2bf(f1.y) << 16);
        o.w = f2bf(f1.z) | ((unsigned)f2bf(f1.w) << 16);
        *reinterpret_cast<uint4*>(xb + i) = o;
    } else {                                  // e: 2048 blocks, 4 rows/block
        const int row  = (bid - 1024) * 4 + (threadIdx.x >> 6);
        const int lane = threadIdx.x & 63;
        const float4 v = *reinterpret_cast<const float4*>(e + (size_t)row * DDIM + lane * 4);
        float s = v.x * v.x + v.y * v.y + v.z * v.z + v.w * v.w;
        #pragma unroll
        for (int off = 1; off < 64; off <<= 1) s += __shfl_xor(s, off);
        const float inv = 1.0f / fmaxf(sqrtf(s), 1e-12f);
        ushort4 o;
        o.x = f2bf(v.x * inv); o.y = f2bf(v.y * inv);
        o.z = f2bf(v.z * inv); o.w = f2bf(v.w * inv);
        *reinterpret_cast<ushort4*>(eb + (size_t)row * DDIM + lane * 4) = o;
    }
}

#define GLOAD_LDS(g, s) \
    __builtin_amdgcn_global_load_lds((const __attribute__((address_space(1))) void*)(g), \
                                     (__attribute__((address_space(3))) void*)(s), 16, 0, 0)

#define SBAR do { asm volatile("" ::: "memory"); __builtin_amdgcn_s_barrier(); \
                  asm volatile("" ::: "memory"); } while (0)
#define WAIT_LGKM(n) do { asm volatile("s_waitcnt lgkmcnt(" #n ")" ::: "memory"); \
                          __builtin_amdgcn_sched_barrier(0); } while (0)
#define WAIT_VM(n) do { asm volatile("s_waitcnt vmcnt(" #n ")" ::: "memory"); \
                        __builtin_amdgcn_sched_barrier(0); } while (0)

// ---------- GEMM: 32-row waves (aF = 64 VGPR), A via LDS, 6-slot B ring ----------
// grid 1024 = 64 panels (128 rows) x 16 splits (512 cols); block = 4 waves x 32 rows.
// XCD X (bid&7) owns panels 8X..8X+7: per-XCD working set = B 4 MB + A 512 KB.
// LDS 48 KB = 6-slot B ring x 8 KB (16 cols x 512 B); A prologue uses [0,32K) in
// 2 serial rounds (rows 64r..64r+63; waves 2r,2r+1 read their 32-row halves).
// Rows 512 B = 32 chunks of 16 B; phys chunk = (p&24)|((p&7)^(row&7)), src pre-swizzled.
// Pair pacing (r14-proven): u=0..15, steady WAIT_VM(4) -> SBAR -> STAGEB pair u+2 -> 2 TILEs.
// NO min-waves launch-bounds arg (r15/r16 spill trap): LDS bounds residency at 3 blocks/CU.
__launch_bounds__(256)
__global__ void k_gemm(const unsigned short* __restrict__ xb,
                       const unsigned short* __restrict__ eb,
                       unsigned* pout /* aliases d_out */) {
    extern __shared__ char smem[];

    const int tid = threadIdx.x;
    const int w = tid >> 6, l = tid & 63;
    const int lg = l >> 4, lr = l & 15, lr7 = lr & 7;
    const int bid = blockIdx.x;
    const int X = bid & 7, q = bid >> 3;              // q in [0,128)
    const int panel = X * 8 + (q >> 4);               // XCD X owns panels 8X..8X+7
    const int split = q & 15;
    const int n0 = panel * 128, c0 = split * 512;

    // ---- staging lane constants: thread t covers chunk c = g*256 + t ----
    const int lchk = (tid & 24) | ((tid & 7) ^ ((tid >> 5) & 7));
    const char* baseA = (const char*)xb + (size_t)(n0 + (tid >> 5)) * 512 + lchk * 16;
    const char* baseB = (const char*)eb + (size_t)(c0 + (tid >> 5)) * 512 + lchk * 16;
    const int wl16 = w * 1024;                 // wave-uniform LDS base

#define STAGE_AH(r) do { _Pragma("unroll") for (int g_ = 0; g_ < 8; ++g_)                  \
    GLOAD_LDS(baseA + (r) * 32768 + g_ * 4096, smem + g_ * 4096 + wl16); } while (0)
#define STAGEB(t) do { _Pragma("unroll") for (int g_ = 0; g_ < 2; ++g_)                    \
    GLOAD_LDS(baseB + (size_t)(t) * 8192 + g_ * 4096,                                      \
              smem + ((t) % 6) * 8192 + g_ * 4096 + wl16); } while (0)

    // ---- A fragments: 32 rows x 256 K per wave = 64 VGPR ----
    bf16x8 aF[2][8];
#define READA() do { _Pragma("unroll") for (int mi_ = 0; mi_ < 2; ++mi_)                   \
    _Pragma("unroll") for (int kk_ = 0; kk_ < 8; ++kk_) {                                  \
        const int lc_ = kk_ * 4 + lg;                                                      \
        const int ph_ = (lc_ & 24) | ((lc_ & 7) ^ lr7);                                    \
        aF[mi_][kk_] = *reinterpret_cast<const bf16x8*>(                                   \
            smem + ((w & 1) * 32 + mi_ * 16 + lr) * 512 + ph_ * 16); } } while (0)

    // ---- prologue: 2 serial A rounds (32 KB); waves 2r,2r+1 read round r ----
    STAGE_AH(0);
    WAIT_VM(0); SBAR;
    if (w < 2) READA();
    WAIT_LGKM(0); SBAR;                        // readers drained before overwrite
    STAGE_AH(1);
    WAIT_VM(0); SBAR;
    if (w >= 2) READA();
    WAIT_LGKM(0); SBAR;
    STAGEB(0); STAGEB(1); STAGEB(2); STAGEB(3);   // pairs 0,1 (8 loads in flight)

    // ---- main loop state ----
    const f32x4 zf4 = {0.f, 0.f, 0.f, 0.f};
    unsigned rk1[8], rk2[8];
    #pragma unroll
    for (int i = 0; i < 8; ++i) { rk1[i] = 0u; rk2[i] = 0u; }

// One 16-col tile: 8 kk x {1 ds_read_b128, 2 MFMA}; kk=0 zero-C; 2-op-key TILEEND.
#define TILE(t) do {                                                                       \
    const char* sb_ = smem + ((t) % 6) * 8192;                                             \
    f32x4 ac0_, ac1_;                                                                      \
    {                                                                                      \
        const int ph0_ = ((lg & 24) | ((lg & 7) ^ lr7)) * 16;                              \
        const bf16x8 b_ = *reinterpret_cast<const bf16x8*>(sb_ + lr * 512 + ph0_);         \
        ac0_ = __builtin_amdgcn_mfma_f32_16x16x32_bf16(aF[0][0], b_, zf4, 0, 0, 0);        \
        ac1_ = __builtin_amdgcn_mfma_f32_16x16x32_bf16(aF[1][0], b_, zf4, 0, 0, 0);        \
    }                                                                                      \
    _Pragma("unroll") for (int kk_ = 1; kk_ < 8; ++kk_) {                                  \
        const int lc_ = kk_ * 4 + lg;                                                      \
        const int ph_ = ((lc_ & 24) | ((lc_ & 7) ^ lr7)) * 16;                             \
        const bf16x8 b_ = *reinterpret_cast<const bf16x8*>(sb_ + lr * 512 + ph_);          \
        ac0_ = __builtin_amdgcn_mfma_f32_16x16x32_bf16(aF[0][kk_], b_, ac0_, 0, 0, 0);     \
        ac1_ = __builtin_amdgcn_mfma_f32_16x16x32_bf16(aF[1][kk_], b_, ac1_, 0, 0, 0);     \
    }                                                                                      \
    const unsigned encb_ = (unsigned)(255 - ((t) & 15) * 16) - (unsigned)lr;               \
    _Pragma("unroll") for (int rr_ = 0; rr_ < 4; ++rr_) {                                  \
        const unsigned q0_ = key32(ac0_[rr_], encb_);                                      \
        const unsigned lo0_ = u32min(rk1[rr_], q0_);                                       \
        rk1[rr_] = u32max(rk1[rr_], q0_);                                                  \
        rk2[rr_] = u32max(rk2[rr_], lo0_);                                                 \
        const unsigned q1_ = key32(ac1_[rr_], encb_);                                      \
        const unsigned lo1_ = u32min(rk1[4 + rr_], q1_);                                   \
        rk1[4 + rr_] = u32max(rk1[4 + rr_], q1_);                                          \
        rk2[4 + rr_] = u32max(rk2[4 + rr_], lo1_);                                         \
    }                                                                                      \
} while (0)

// flush: merge the 16 lr-lanes' running top-2, store this half's partials, reset
#define FLUSH(half) do {                                                                   \
    _Pragma("unroll") for (int i_ = 0; i_ < 8; ++i_) {                                     \
        unsigned t1_ = rk1[i_], t2_ = rk2[i_];                                             \
        _Pragma("unroll") for (int off_ = 1; off_ < 16; off_ <<= 1) {                      \
            const unsigned o1_ = __shfl_xor(t1_, off_);                                    \
            const unsigned o2_ = __shfl_xor(t2_, off_);                                    \
            const unsigned n1_ = u32max(t1_, o1_), lo_ = u32min(t1_, o1_);                 \
            t2_ = u32max(u32max(t2_, o2_), lo_);                                           \
            t1_ = n1_;                                                                     \
        }                                                                                  \
        if (lr == 0) {                                                                     \
            const int row_ = n0 + w * 32 + (i_ >> 2) * 16 + lg * 4 + (i_ & 3);             \
            uint2 o_; o_.x = t1_; o_.y = t2_;                                              \
            *reinterpret_cast<uint2*>(pout + (size_t)row_ * 256 + split * 4 + (half) * 2) = o_; \
        }                                                                                  \
        rk1[i_] = 0u; rk2[i_] = 0u;                                                        \
    }                                                                                      \
} while (0)

    // ---- 16 pairs of 16-col tiles; one WAIT_VM + SBAR per pair ----
    // FIFO (per wave, 4 loads/pair): entering u, outstanding = pairs u,u+1 (8) ->
    // VM(4) retires pair u; SBAR certifies on all waves; STAGEB(pair u+2) overwrites
    // slots (2u+4)%6 = (2u-2)%6 whose last readers (pair u-1) all passed SBAR(u).
    // FLUSH(0) stores at u=7: bounded over-wait at u=8/9 (r13-proven safe pattern).
    WAIT_VM(4); SBAR;
    #pragma unroll 1
    for (int u = 0; u < 16; ++u) {
        if (u >= 1) {
            if (u < 15) { WAIT_VM(4); } else { WAIT_VM(0); }
            SBAR;
        }
        if (u <= 13) { STAGEB(2 * u + 4); STAGEB(2 * u + 5); }
        TILE(2 * u);
        TILE(2 * u + 1);
        if (u == 7)  FLUSH(0);                // tiles 0-15 = first 256-col half
        if (u == 15) FLUSH(1);                // second half
    }
#undef STAGE_AH
#undef STAGEB
#undef READA
#undef TILE
#undef FLUSH
}

// ---------- fixup: global top-4 of 64 keys -> exact f32 -> argmax + gather ----------
__global__ void k_fixup(const unsigned* pk,  // == (u32*)d_out, intentionally no restrict
                        const float* __restrict__ x, const float* __restrict__ e,
                        float* out) {
    const int row = blockIdx.x * 4 + (threadIdx.x >> 6);
    const int t   = threadIdx.x & 63;   // t<32: half-split partial holder (256 cols each)
    unsigned long long kk0 = 0ull, kk1 = 0ull;
    if (t < 32) {
        const uint2 kv = reinterpret_cast<const uint2*>(pk + (size_t)row * 256)[t];
        const int col0 = t * 256 + 255 - (int)(kv.x & 255u);
        kk0 = ((unsigned long long)(kv.x & 0xFFFFFF00u) << 32) | (unsigned)(~col0);
        const int col1 = t * 256 + 255 - (int)(kv.y & 255u);
        kk1 = ((unsigned long long)(kv.y & 0xFFFFFF00u) << 32) | (unsigned)(~col1);
    }

    int cand[4];
    #pragma unroll
    for (int p = 0; p < 4; ++p) {
        unsigned long long m = kk0 > kk1 ? kk0 : kk1;
        #pragma unroll
        for (int off = 1; off < 64; off <<= 1) {
            const unsigned long long o = __shfl_xor(m, off);
            if (o > m) m = o;
        }
        cand[p] = (int)(~(unsigned)m) & (CCNT - 1);
        if (kk0 == m) kk0 = 0ull;
        if (kk1 == m) kk1 = 0ull;
    }

    const float4 xv = *reinterpret_cast<const float4*>(x + (size_t)row * DDIM + t * 4);
    float best = -INFINITY; int bc = 0x7fffffff;
    #pragma unroll
    for (int p = 0; p < 4; ++p) {
        const int c = cand[p];
        const float4 ev = *reinterpret_cast<const float4*>(e + (size_t)c * DDIM + t * 4);
        float d  = xv.x * ev.x + xv.y * ev.y + xv.z * ev.z + xv.w * ev.w;
        float ss = ev.x * ev.x + ev.y * ev.y + ev.z * ev.z + ev.w * ev.w;
        #pragma unroll
        for (int off = 1; off < 64; off <<= 1) {
            d  += __shfl_xor(d, off);
            ss += __shfl_xor(ss, off);
        }
        const float v = d * (1.0f / fmaxf(sqrtf(ss), 1e-12f));
        if (v > best || (v == best && c < bc)) { best = v; bc = c; }
    }

    if (t == 0) out[(size_t)QROWS * DDIM + row] = (float)bc;
    const float4 qv = *reinterpret_cast<const float4*>(e + (size_t)bc * DDIM + t * 4);
    *reinterpret_cast<float4*>(out + (size_t)row * DDIM + t * 4) = qv; // overwrites this row's partials only
}

extern "C" void kernel_launch(void* const* d_in, const int* in_sizes, int n_in,
                              void* d_out, int out_size, void* d_ws, size_t ws_size,
                              hipStream_t stream) {
    const float* x = (const float*)d_in[0];
    const float* e = (const float*)d_in[1];
    float* out = (float*)d_out;
    char* ws = (char*)d_ws;

    unsigned short* xb = (unsigned short*)ws;                             // 4 MB
    unsigned short* eb = (unsigned short*)(ws + (size_t)4 * 1024 * 1024); // 4 MB

    hipFuncSetAttribute(reinterpret_cast<const void*>(k_gemm),
                        hipFuncAttributeMaxDynamicSharedMemorySize, 49152);

    k_prep<<<3072, 256, 0, stream>>>(x, xb, e, eb);
    k_gemm<<<1024, 256, 49152, stream>>>(xb, eb, (unsigned*)d_out);
    k_fixup<<<QROWS / 4, 256, 0, stream>>>((const unsigned*)d_out, x, e, out);
}